// Round 1
// baseline (547.961 us; speedup 1.0000x reference)
//
#include <hip/hip_runtime.h>
#include <math.h>

#define S_LEN 2048
#define DHEAD 128
#define NHEAD 16
#define QBLK  64
#define KVBLK 64
#define NQT   (S_LEN / QBLK)          // 32 q-tiles
#define ATT_SCALE 0.08838834764831845f // 1/sqrt(128)

// LDS pitches (bf16 elements). Multiples of 8 so ds_read_b128 stays 16B-aligned.
// KP=136: frag-read banks conflict-free, staging writes ~4-way.
// VP=PP=72: frag reads conflict-free, staging/P writes ~free/4-way.
#define KP 136
#define VP 72
#define PP 72

typedef __attribute__((ext_vector_type(4))) float f32x4;
typedef __attribute__((ext_vector_type(8))) short s16x8;

__device__ __forceinline__ unsigned f2bfu(float f) {
  union { float ff; unsigned u; } x; x.ff = f;
  return (x.u + 0x7fffu + ((x.u >> 16) & 1u)) >> 16;   // RNE f32->bf16
}
__device__ __forceinline__ short f2bf(float f) { return (short)f2bfu(f); }
__device__ __forceinline__ int pack2(float lo, float hi) {
  return (int)(f2bfu(lo) | (f2bfu(hi) << 16));
}

__global__ __launch_bounds__(256, 2)
void alibi_attn_fwd(const float* __restrict__ Qg, const float* __restrict__ Kg,
                    const float* __restrict__ Vg, float* __restrict__ Og)
{
  __shared__ __align__(16) short kt[KVBLK * KP];    // K tile, row-major [kv][d]
  __shared__ __align__(16) short vt[DHEAD * VP];    // V tile, transposed [d][kv]
  __shared__ __align__(16) short pl[4][16 * PP];    // per-wave P tile [qrow][kv]

  const int tid  = threadIdx.x;
  const int lane = tid & 63;
  const int w    = tid >> 6;      // wave 0..3 (owns q rows 16w..16w+15)
  const int l16  = lane & 15;
  const int lg   = lane >> 4;     // 0..3

  const int bh   = blockIdx.x / NQT;   // 0..63 (b*H + h)
  const int qt   = blockIdx.x % NQT;
  const int qb   = qt * QBLK;
  const int head = bh & (NHEAD - 1);

  const size_t base = (size_t)bh * S_LEN * DHEAD;
  const float* Q = Qg + base;
  const float* K = Kg + base;
  const float* V = Vg + base;
  float*       O = Og + base;

  // h=16 is a power of two: slope_h = 2^(-0.5*(h+1)), exact in exp2f
  const float slope = exp2f(-0.5f * (float)(head + 1));

  // ---- Q A-fragments in registers (bf16): row = qb+16w+l16, chunk c: d=32c+8lg..+7
  s16x8 qf[4];
  {
    const float* qp = Q + (size_t)(qb + 16*w + l16) * DHEAD + 8*lg;
    #pragma unroll
    for (int c = 0; c < 4; ++c) {
      f32x4 a = *(const f32x4*)(qp + 32*c);
      f32x4 b = *(const f32x4*)(qp + 32*c + 4);
      s16x8 f;
      f[0]=f2bf(a[0]); f[1]=f2bf(a[1]); f[2]=f2bf(a[2]); f[3]=f2bf(a[3]);
      f[4]=f2bf(b[0]); f[5]=f2bf(b[1]); f[6]=f2bf(b[2]); f[7]=f2bf(b[3]);
      qf[c] = f;
    }
  }

  f32x4 oacc[8];
  const f32x4 zero4 = {0.f, 0.f, 0.f, 0.f};
  #pragma unroll
  for (int dt = 0; dt < 8; ++dt) oacc[dt] = zero4;
  float mrun[4] = {-1e30f, -1e30f, -1e30f, -1e30f};
  float lrun[4] = {0.f, 0.f, 0.f, 0.f};

  // K staging map: rows ks_r0..+3, d = ks_d0..+7 per thread
  const int ks_r0 = 4 * (tid >> 4);
  const int ks_d0 = 8 * (tid & 15);
  // V staging map: row pair (vs_j0, vs_j0+1), d = vs_d0..+15 per thread
  const int vs_j0 = 2 * (tid & 31);
  const int vs_d0 = 16 * (tid >> 5);

  const int kvend = qb + QBLK;   // causal: only kv < qb+QBLK needed
  for (int kv0 = 0; kv0 < kvend; kv0 += KVBLK) {
    // ---- issue global loads for staging (overlap with prior PV latency) ----
    f32x4 ka[4][2];
    {
      const float* kp = K + (size_t)(kv0 + ks_r0) * DHEAD + ks_d0;
      #pragma unroll
      for (int rr = 0; rr < 4; ++rr) {
        ka[rr][0] = *(const f32x4*)(kp + rr * DHEAD);
        ka[rr][1] = *(const f32x4*)(kp + rr * DHEAD + 4);
      }
    }
    f32x4 va[4], vb[4];
    {
      const float* vp = V + (size_t)(kv0 + vs_j0) * DHEAD + vs_d0;
      #pragma unroll
      for (int e = 0; e < 4; ++e) {
        va[e] = *(const f32x4*)(vp + 4*e);
        vb[e] = *(const f32x4*)(vp + DHEAD + 4*e);
      }
    }

    __syncthreads();   // all waves done reading kt/vt from previous iteration

    // ---- stage K tile (bf16 row-major) ----
    #pragma unroll
    for (int rr = 0; rr < 4; ++rr) {
      #pragma unroll
      for (int e = 0; e < 4; ++e) {
        float lo = ka[rr][e >> 1][(e & 1) * 2];
        float hi = ka[rr][e >> 1][(e & 1) * 2 + 1];
        *(int*)&kt[(ks_r0 + rr) * KP + ks_d0 + 2*e] = pack2(lo, hi);
      }
    }
    // ---- stage V^T tile (bf16, [d][kv]) ----
    #pragma unroll
    for (int e = 0; e < 4; ++e) {
      #pragma unroll
      for (int q2 = 0; q2 < 4; ++q2) {
        int d = vs_d0 + 4*e + q2;
        *(int*)&vt[d * VP + vs_j0] = pack2(va[e][q2], vb[e][q2]);
      }
    }
    __syncthreads();   // tiles visible to all waves

    // ---- QK^T: S[16 x 64] per wave, A=Q frag, B=K row-frags from LDS ----
    f32x4 sacc[4];
    #pragma unroll
    for (int nt = 0; nt < 4; ++nt) sacc[nt] = zero4;
    #pragma unroll
    for (int c = 0; c < 4; ++c) {
      #pragma unroll
      for (int nt = 0; nt < 4; ++nt) {
        s16x8 kf = *(const s16x8*)&kt[(nt*16 + l16) * KP + 32*c + 8*lg];
        sacc[nt] = __builtin_amdgcn_mfma_f32_16x16x32_bf16(qf[c], kf, sacc[nt], 0, 0, 0);
      }
    }

    // ---- online softmax (D-layout: row = 4lg+r, col = nt*16+l16) ----
    #pragma unroll
    for (int r = 0; r < 4; ++r) {
      const int i = qb + 16*w + 4*lg + r;    // global q row
      float sv[4];
      float mx = -1e30f;
      #pragma unroll
      for (int nt = 0; nt < 4; ++nt) {
        const int j = kv0 + nt*16 + l16;     // global kv col
        float sval = sacc[nt][r] * ATT_SCALE + (float)(j - i) * slope;
        sval = (j > i) ? -1e30f : sval;      // causal mask
        sv[nt] = sval;
        mx = fmaxf(mx, sval);
      }
      #pragma unroll
      for (int off = 1; off < 16; off <<= 1)
        mx = fmaxf(mx, __shfl_xor(mx, off));           // row-max across 16-lane group
      const float mo = mrun[r];
      const float mn = (mx > mo + 8.0f) ? mx : mo;     // defer-max (T13, THR=8)
      float rs = 0.f;
      #pragma unroll
      for (int nt = 0; nt < 4; ++nt) {
        float p = __expf(sv[nt] - mn);                 // <= e^8, fine in bf16
        rs += p;
        pl[w][(4*lg + r) * PP + nt*16 + l16] = f2bf(p);
      }
      #pragma unroll
      for (int off = 1; off < 16; off <<= 1)
        rs += __shfl_xor(rs, off);                     // row-sum
      if (mn != mo) {
        const float corr = __expf(mo - mn);
        lrun[r] = lrun[r] * corr + rs;
        #pragma unroll
        for (int dt = 0; dt < 8; ++dt) oacc[dt][r] *= corr;
        mrun[r] = mn;
      } else {
        lrun[r] += rs;
      }
    }

    // ---- PV: O[16 x 128] += P[16 x 64] * V[64 x 128] ----
    #pragma unroll
    for (int c2 = 0; c2 < KVBLK/32; ++c2) {
      s16x8 pa = *(const s16x8*)&pl[w][l16 * PP + c2*32 + 8*lg];
      #pragma unroll
      for (int dt = 0; dt < 8; ++dt) {
        s16x8 bv = *(const s16x8*)&vt[(dt*16 + l16) * VP + c2*32 + 8*lg];
        oacc[dt] = __builtin_amdgcn_mfma_f32_16x16x32_bf16(pa, bv, oacc[dt], 0, 0, 0);
      }
    }
  }

  // ---- epilogue: normalize and store fp32 ----
  #pragma unroll
  for (int r = 0; r < 4; ++r) {
    const float inv = 1.0f / lrun[r];
    float* op = O + (size_t)(qb + 16*w + 4*lg + r) * DHEAD + l16;
    #pragma unroll
    for (int dt = 0; dt < 8; ++dt) op[dt * 16] = oacc[dt][r] * inv;
  }
}

extern "C" void kernel_launch(void* const* d_in, const int* in_sizes, int n_in,
                              void* d_out, int out_size, void* d_ws, size_t ws_size,
                              hipStream_t stream) {
  (void)in_sizes; (void)n_in; (void)out_size; (void)d_ws; (void)ws_size;
  const float* q = (const float*)d_in[0];
  const float* k = (const float*)d_in[1];
  const float* v = (const float*)d_in[2];
  float* o = (float*)d_out;
  dim3 grid(64 * NQT);   // (b*h)=64 heads x 32 q-tiles = 2048 blocks
  dim3 block(256);
  alibi_attn_fwd<<<grid, block, 0, stream>>>(q, k, v, o);
}